// Round 5
// baseline (760.119 us; speedup 1.0000x reference)
//
#include <hip/hip_runtime.h>

typedef unsigned short u16;
typedef unsigned long long u64;
typedef __attribute__((ext_vector_type(8))) __bf16 bf16x8;
typedef __attribute__((ext_vector_type(4))) float f32x4;

#define DT_STEP 0.01f

// ---- workspace layout (bytes) ----
// Staged layout: element (row,kk) of a [rows x K] K-major matrix at
//   off_u16 = ((row>>4)*KB + (kk>>5))*512 + (((kk>>3)&3)*16 + (row&15))*8 + (kk&7)
// -> a wave's MFMA fragment load is 16B/lane at base + lane*16B; 8
//    consecutive kk of one row are 16B contiguous (coalesced stores).
//    A (row-block, k-chunk) unit is 1KB, lane-linear -> global_load_lds-able;
//    consecutive k-chunks of one row-block are contiguous (2KB units OK).
//
// Wall : 4480 rows x 512 K (KB=16, 280 row-blocks)
// Aop2 : 496 rows x 5632 K (KB=176) : KB 0..127 Tflat, KB 128..143 T9
// Bop2 : 496 rows x 5632 K (KB=176) : KB 0..127 SwT, KB 144..175 rho slots
//
// R3 LESSON (journal): device-scope fences (__threadfence) in per-step
// kernels flush/invalidate XCD L2 on gfx950 -> phaseB reads fell out of
// cache (FETCH 11.7MB, 70us/dispatch). No cross-block protocols in the
// hot loop; phase B stays block-local.  R4: phaseB slot ~12.9us/step on
// 136/256 CUs -> R5 output-splits it to 272 blocks (bitwise-identical).
static const size_t OFF_WALL = 0;
static const size_t OFF_AOP2 = 4587520;    // 280*16*512*2
static const size_t OFF_BOP2 = 10174464;   // + 31*176*512*2
static const size_t WS_NEED  = 16221440;   // proven available since R0

static __device__ __forceinline__ u16 f2bf(float x){
  unsigned u = __float_as_uint(x);
  u = u + 0x7FFFu + ((u >> 16) & 1u);   // RNE
  return (u16)(u >> 16);
}
static __device__ __forceinline__ float bf2f(u16 h){
  return __uint_as_float(((unsigned)h) << 16);
}

static __device__ __forceinline__ size_t stx(int row, int kk, int KB){
  return ((size_t)((row >> 4) * KB + (kk >> 5)) << 9)
       + (size_t)(((((kk >> 3) & 3) * 16) + (row & 15)) << 3) + (kk & 7);
}

// Rotated-register-pipeline NT GEMM K-loop on staged operands (all cached).
// Requires (NKT-DEPTH) % DEPTH == 0.  (Used by gemmG_k.)
template<int NKT, int DEPTH>
static __device__ __forceinline__ void kloop(
    f32x4 (&acc)[2][2], const u16* __restrict__ baseA,
    const u16* __restrict__ baseB, size_t strA, size_t strB)
{
  bf16x8 Ar[DEPTH][2], Br[DEPTH][2];
#define LDAB(p, kt) { const u16* pa = baseA + ((size_t)(kt) << 9);             \
    const u16* pb = baseB + ((size_t)(kt) << 9);                               \
    Ar[p][0] = *(const bf16x8*)pa; Ar[p][1] = *(const bf16x8*)(pa + strA);     \
    Br[p][0] = *(const bf16x8*)pb; Br[p][1] = *(const bf16x8*)(pb + strB); }
#define MF(p) \
    acc[0][0] = __builtin_amdgcn_mfma_f32_16x16x32_bf16(Ar[p][0], Br[p][0], acc[0][0], 0, 0, 0); \
    acc[0][1] = __builtin_amdgcn_mfma_f32_16x16x32_bf16(Ar[p][0], Br[p][1], acc[0][1], 0, 0, 0); \
    acc[1][0] = __builtin_amdgcn_mfma_f32_16x16x32_bf16(Ar[p][1], Br[p][0], acc[1][0], 0, 0, 0); \
    acc[1][1] = __builtin_amdgcn_mfma_f32_16x16x32_bf16(Ar[p][1], Br[p][1], acc[1][1], 0, 0, 0);
  #pragma unroll
  for (int p = 0; p < DEPTH; ++p){ LDAB(p, p) }
  for (int it = 0; it < NKT - DEPTH; it += DEPTH){
    #pragma unroll
    for (int p = 0; p < DEPTH; ++p){
      MF(p)
      LDAB(p, it + p + DEPTH)
    }
  }
  #pragma unroll
  for (int p = 0; p < DEPTH; ++p){ MF(p) }
#undef LDAB
#undef MF
}

// Half-tile (16 x 32) variant: 1 A row-block, 2 B row-blocks, 2 MFMA/iter.
template<int NKT, int DEPTH>
static __device__ __forceinline__ void kloopH(
    f32x4 (&acc)[2], const u16* __restrict__ baseA,
    const u16* __restrict__ baseB, size_t strB)
{
  bf16x8 Ar[DEPTH], Br[DEPTH][2];
#define LDABH(p, kt) { const u16* pa = baseA + ((size_t)(kt) << 9);            \
    const u16* pb = baseB + ((size_t)(kt) << 9);                               \
    Ar[p] = *(const bf16x8*)pa;                                                \
    Br[p][0] = *(const bf16x8*)pb; Br[p][1] = *(const bf16x8*)(pb + strB); }
#define MFH(p) \
    acc[0] = __builtin_amdgcn_mfma_f32_16x16x32_bf16(Ar[p], Br[p][0], acc[0], 0, 0, 0); \
    acc[1] = __builtin_amdgcn_mfma_f32_16x16x32_bf16(Ar[p], Br[p][1], acc[1], 0, 0, 0);
  #pragma unroll
  for (int p = 0; p < DEPTH; ++p){ LDABH(p, p) }
  for (int it = 0; it < NKT - DEPTH; it += DEPTH){
    #pragma unroll
    for (int p = 0; p < DEPTH; ++p){
      MFH(p)
      LDABH(p, it + p + DEPTH)
    }
  }
  #pragma unroll
  for (int p = 0; p < DEPTH; ++p){ MFH(p) }
#undef LDABH
#undef MFH
}

// K0a: fill Wall k=0..7 (staged) and SwT region of Bop2. K-pads -> 0.
__global__ __launch_bounds__(256) void k0a(const float* __restrict__ L,
                                           const float* __restrict__ rates,
                                           u16* __restrict__ Wall,
                                           u16* __restrict__ Bop2){
  int id = blockIdx.x * 256 + threadIdx.x;
  if (id >= 8*496*512) return;
  int k   = id / (496*512);
  int rem = id - k*(496*512);
  int i   = rem >> 9;
  int j   = rem & 511;
  float rt = sqrtf(fabsf(rates[k]));
  float v = 0.0f;
  if (j < 496) v = rt * L[(size_t)k*246016 + i*496 + j];
  u16 h = f2bf(v);
  Wall[stx(k*496 + i, j, 16)] = h;
  Bop2[stx(i, (k << 9) + j, 176)] = h;
}

// K0b: SwC[i, k*512+j] = sqrt(r_k)*L_k[j,i] into Aop2 KB 0..127 (LDS
// transpose). Consumed once by gemmG, then overwritten by Tflat each step.
__global__ __launch_bounds__(256) void k0b(const float* __restrict__ L,
                                           const float* __restrict__ rates,
                                           u16* __restrict__ Aop2){
  __shared__ float tile[32][33];
  int k  = blockIdx.z;
  int i0 = blockIdx.x * 32;
  int j0 = blockIdx.y * 32;
  int tx = threadIdx.x, ty = threadIdx.y;  // 32 x 8
  float rt = sqrtf(fabsf(rates[k]));
  #pragma unroll
  for (int p = 0; p < 4; ++p){
    int j = j0 + ty + p*8;
    int i = i0 + tx;
    float v = 0.0f;
    if (j < 496 && i < 496) v = rt * L[(size_t)k*246016 + j*496 + i];
    tile[ty + p*8][tx] = v;
  }
  __syncthreads();
  #pragma unroll
  for (int p = 0; p < 4; ++p){
    int i = i0 + ty + p*8;
    int j = j0 + tx;
    if (i < 496) Aop2[stx(i, (k << 9) + j, 176)] = f2bf(tile[tx][ty + p*8]);
  }
}

// K0c: rho into Bop2 slot0, zero slot1, d_out = rho0, Wall pads zero.
__global__ __launch_bounds__(256) void k0c(const float* __restrict__ rho0,
                                           u16* __restrict__ Bop2,
                                           u16* __restrict__ Wall,
                                           float* __restrict__ dout){
  int id = blockIdx.x * 256 + threadIdx.x;
  if (id >= 496*512) return;
  int i = id >> 9, j = id & 511;
  float f = (j < 496) ? rho0[(size_t)i*496 + j] : 0.0f;
  Bop2[stx(i, 4608 + j, 176)] = f2bf(f);
  Bop2[stx(i, 5120 + j, 176)] = 0;
  if (j < 496) dout[(size_t)i*496 + j] = f;
  // Wall pad rows 4464..4479 (all cols)
  if (id < 8192) Wall[stx(4464 + (id >> 9), id & 511, 16)] = 0;
  // Wall G-block K-pad cols 496..511 for rows 3968..4463
  else if (id < 8192 + 7936){
    int idx = id - 8192;
    Wall[stx(3968 + (idx >> 4), 496 + (idx & 15), 16)] = 0;
  }
}

// G = SwC * SwC^T (once) -> Wall rows 3968..4463 (staged, KB=16).
__global__ __launch_bounds__(256, 2) void gemmG_k(
    const u16* __restrict__ Asrc, u16* __restrict__ Wall){
  const int t = threadIdx.x, lane = t & 63, w = t >> 6;
  const int wm = w & 1, wn = w >> 1;
  const int tm = blockIdx.x, tn = blockIdx.y;
  const size_t laneu = (size_t)lane * 8;
  const size_t str = (size_t)176 << 9;
  const u16* baseA = Asrc + (((size_t)(tm*4 + wm*2) * 176) << 9) + laneu;
  const u16* baseB = Asrc + (((size_t)(tn*4 + wn*2) * 176) << 9) + laneu;
  f32x4 acc[2][2];
  #pragma unroll
  for (int a = 0; a < 2; ++a)
    #pragma unroll
    for (int b = 0; b < 2; ++b)
      acc[a][b] = (f32x4){0.f, 0.f, 0.f, 0.f};
  kloop<128, 4>(acc, baseA, baseB, str, str);
  const int quad = lane >> 4, c16 = lane & 15;
  #pragma unroll
  for (int mi = 0; mi < 2; ++mi)
  #pragma unroll
  for (int ni = 0; ni < 2; ++ni)
  #pragma unroll
  for (int r = 0; r < 4; ++r){
    int row = tm*64 + wm*32 + mi*16 + quad*4 + r;
    int col = tn*64 + wn*32 + ni*16 + c16;
    if (row < 496 && col < 496)
      Wall[stx(3968 + row, col, 16)] = f2bf(acc[mi][ni][r]);
  }
}

// Phase A v3 (R3/R4-measured ~9.5us/step incl. launch gap): LDS-staged via
// global_load_lds width=16, 2-chunk (2KB) units: 8 iterations x 8 MFMA,
// 16 barriers, vmcnt(4), 32KB LDS dbuf.
typedef const __attribute__((address_space(1))) unsigned char* gas1p;
typedef __attribute__((address_space(3))) unsigned char* las3p;

__global__ __launch_bounds__(256, 4) void phaseA_k(
    const u16* __restrict__ Wall, const u16* __restrict__ Bop2,
    int rhoKB, u16* __restrict__ Aop2)
{
  __shared__ char smraw[32768];                     // 2 bufs x 8 units x 2KB
  u16 (*stage)[8][1024] = (u16 (*)[8][1024])smraw;  // [2][8 units][1024 u16]
  float (*T)[66] = (float (*)[66])smraw;            // epilogue transpose alias

  int b = blockIdx.x;
  int x = b & 7, i = b >> 3;
  int tm = x*9 + (i % 9);
  int tn = i / 9;
  if (tm >= 70) return;                      // block-uniform early exit
  const int t = threadIdx.x, lane = t & 63, w = t >> 6;
  const int wm = w & 1, wn = w >> 1;
  const int lane8 = lane * 8;                // lane*16B in u16 units

  // Wave w stages A row-block tm*4+w (Wall) and B row-block tn*4+w (rho).
  const u16* gAw = Wall + (((size_t)(tm*4 + w) * 16) << 9) + lane8;
  const u16* gBw = Bop2 + (((size_t)(tn*4 + w) * 176 + rhoKB) << 9) + lane8;

  // stage 2 consecutive k-chunks (2j, 2j+1) per unit: 4 loads/wave/iter
#define STAGE_A(bi, j) {                                                       \
    size_t ko = (size_t)((j) * 2) << 9;                                        \
    __builtin_amdgcn_global_load_lds((gas1p)(gAw + ko),                        \
        (las3p)&stage[bi][w][0], 16, 0, 0);                                    \
    __builtin_amdgcn_global_load_lds((gas1p)(gAw + ko + 512),                  \
        (las3p)&stage[bi][w][512], 16, 0, 0);                                  \
    __builtin_amdgcn_global_load_lds((gas1p)(gBw + ko),                        \
        (las3p)&stage[bi][4 + w][0], 16, 0, 0);                                \
    __builtin_amdgcn_global_load_lds((gas1p)(gBw + ko + 512),                  \
        (las3p)&stage[bi][4 + w][512], 16, 0, 0); }

  f32x4 acc[2][2];
  #pragma unroll
  for (int a = 0; a < 2; ++a)
    #pragma unroll
    for (int c = 0; c < 2; ++c)
      acc[a][c] = (f32x4){0.f, 0.f, 0.f, 0.f};

#define COMPUTE_A(bi) {                                                        \
    _Pragma("unroll")                                                          \
    for (int c = 0; c < 2; ++c){                                               \
      bf16x8 a0 = *(const bf16x8*)&stage[bi][wm*2 + 0][c*512 + lane8];         \
      bf16x8 a1 = *(const bf16x8*)&stage[bi][wm*2 + 1][c*512 + lane8];         \
      bf16x8 b0 = *(const bf16x8*)&stage[bi][4 + wn*2 + 0][c*512 + lane8];     \
      bf16x8 b1 = *(const bf16x8*)&stage[bi][4 + wn*2 + 1][c*512 + lane8];     \
      acc[0][0] = __builtin_amdgcn_mfma_f32_16x16x32_bf16(a0, b0, acc[0][0], 0, 0, 0); \
      acc[0][1] = __builtin_amdgcn_mfma_f32_16x16x32_bf16(a0, b1, acc[0][1], 0, 0, 0); \
      acc[1][0] = __builtin_amdgcn_mfma_f32_16x16x32_bf16(a1, b0, acc[1][0], 0, 0, 0); \
      acc[1][1] = __builtin_amdgcn_mfma_f32_16x16x32_bf16(a1, b1, acc[1][1], 0, 0, 0); \
    } }

  // prologue: 2 double-chunk units in flight (8 loads)
  STAGE_A(0, 0)
  STAGE_A(1, 1)
  int cur = 0;
  #pragma unroll
  for (int j = 0; j < 7; ++j){
    asm volatile("s_waitcnt vmcnt(4)" ::: "memory");  // oldest unit landed
    __builtin_amdgcn_s_barrier();                     // visible to all waves
    COMPUTE_A(cur)
    asm volatile("" ::: "memory");
    __builtin_amdgcn_s_barrier();                     // all reads of cur done
    if (j < 6) STAGE_A(cur, j + 2)                    // restage same parity
    cur ^= 1;
  }
  // peeled last unit (j = 7): drain fully
  asm volatile("s_waitcnt vmcnt(0)" ::: "memory");
  __builtin_amdgcn_s_barrier();
  COMPUTE_A(cur)
#undef STAGE_A
#undef COMPUTE_A

  __syncthreads();   // all waves done with stage[] before aliasing as T

  const int quad = lane >> 4, c16 = lane & 15;
  #pragma unroll
  for (int mi = 0; mi < 2; ++mi)
  #pragma unroll
  for (int ni = 0; ni < 2; ++ni)
  #pragma unroll
  for (int r = 0; r < 4; ++r)
    T[wm*32 + mi*16 + quad*4 + r][wn*32 + ni*16 + c16] = acc[mi][ni][r];
  __syncthreads();
  #pragma unroll
  for (int rep = 0; rep < 2; ++rep){
    int tt = t + rep*256;
    int lr = tt >> 3, oct = tt & 7;
    int row = tm*64 + lr;
    if (row < 4464){
      int colb = tn*64 + oct*8;
      int k = row / 496, i2 = row - k*496;
      union { u16 h[8]; u64 q[2]; } P;
      #pragma unroll
      for (int j = 0; j < 8; ++j)
        P.h[j] = (colb + j < 496) ? f2bf(T[lr][oct*8 + j]) : (u16)0;
      u64* dst = (u64*)&Aop2[stx(i2, (k << 9) + colb, 176)];
      dst[0] = P.q[0]; dst[1] = P.q[1];
    }
  }
}

// Phase-B pair decode with XCD quadrant grouping (R5-proven).
static __device__ __forceinline__ void pairDecode(int b, int& tm, int& tn){
  const int x = b & 7;
  const int o = b >> 3;
  if (x < 6 && o < 16){
    const int qa[6] = {0,0,0,1,1,2};
    const int qb[6] = {1,2,3,2,3,3};
    tm = qa[x]*4 + (o >> 2);
    tn = qb[x]*4 + (o & 3);
  } else {
    int n, grp;
    if (x == 6){ grp = 0; n = o; }
    else if (x == 7){ grp = 1; n = o; }
    else if (x < 3){ grp = 0; n = 17 + x; }
    else { grp = 1; n = 17 + (x - 3); }
    int qbase = (grp == 0) ? ((n < 10) ? 0 : 1) : ((n < 10) ? 2 : 3);
    int m = (n < 10) ? n : n - 10;
    int ii = 0;
    while (m >= 4 - ii){ m -= 4 - ii; ++ii; }
    tm = qbase*4 + ii;
    tn = qbase*4 + ii + m;
  }
}

// Phase B v3 (output-split, fence-free, bitwise-identical to v2):
// 272 blocks: half = (b>=136), pair = b-136*half; 136 = 17*8 so b and b+136
// map to the same XCD slice (shared B-strip in that XCD's L2).
// Each block computes a 16x32 half-tile: rows tm*32+half*16.., cols tn*32..
// 8-wave K-split (identical per-wave K ranges and sum order as v2).
// Epilogue block-local: dout rows (16x32) + mirror cols (32x16),
// staged bf16 rho direct (16 rows) + mirror (32 rows x 16 cols).
__global__ __launch_bounds__(512, 2) void phaseB_k(
    const u16* __restrict__ Aop2, u16* __restrict__ Bop2,
    float* __restrict__ dout, int rhoKBN)
{
  __shared__ float red[8][16][33];
  const int b = (int)blockIdx.x;
  const int half = (b >= 136) ? 1 : 0;
  const int pair = b - 136*half;
  const int t = threadIdx.x, lane = t & 63, w = t >> 6;   // w in 0..7
  int tm, tn;
  pairDecode(pair, tm, tn);                  // tm <= tn
  const size_t laneu = (size_t)lane * 8;
  const size_t str = (size_t)176 << 9;
  const u16* baseA = Aop2 + (((size_t)(tm*2 + half) * 176) << 9) + laneu
                   + ((size_t)(w*16) << 9);
  const u16* baseB = Bop2 + (((size_t)(tn*2) * 176) << 9) + laneu
                   + ((size_t)(w*16) << 9);

  f32x4 acc[2];
  acc[0] = (f32x4){0.f, 0.f, 0.f, 0.f};
  acc[1] = (f32x4){0.f, 0.f, 0.f, 0.f};
  kloopH<16, 8>(acc, baseA, baseB, str);

  const int quad = lane >> 4, c16 = lane & 15;
  #pragma unroll
  for (int ni = 0; ni < 2; ++ni)
  #pragma unroll
  for (int r = 0; r < 4; ++r)
    red[w][quad*4 + r][ni*16 + c16] = acc[ni][r];
  __syncthreads();

  // pass 1: 8-wave reduce + T9 anticommutator + rho update; one elem/thread
  {
    int lr = t >> 5, lc = t & 31;            // 16 x 32 elements
    float sum = 0.0f;
    #pragma unroll
    for (int ww = 0; ww < 8; ++ww) sum += red[ww][lr][lc];
    int row = tm*32 + half*16 + lr, col = tn*32 + lc;
    float rnew = 0.0f;
    if (row < 496 && col < 496){
      float t9a = bf2f(Aop2[stx(row, 4096 + col, 176)]);
      float t9b = bf2f(Aop2[stx(col, 4096 + row, 176)]);
      int e = row*496 + col;
      rnew = dout[e] + DT_STEP * (sum - 0.5f*(t9a + t9b));
      dout[e] = rnew;
      if (tm != tn) dout[col*496 + row] = rnew;
    }
    red[0][lr][lc] = rnew;
  }
  __syncthreads();

  // pass 2: staged bf16 rho, 16B coalesced stores
  if (t < 64){
    // direct: 16 rows x 4 octs
    int lr = t >> 2, oct = t & 3;
    int row = tm*32 + half*16 + lr, colb = tn*32 + oct*8;
    if (row < 496 && colb < 496){
      union { u16 h[8]; u64 q[2]; } B_;
      #pragma unroll
      for (int j = 0; j < 8; ++j) B_.h[j] = f2bf(red[0][lr][oct*8 + j]);
      u64* dst = (u64*)&Bop2[stx(row, (rhoKBN << 5) + colb, 176)];
      dst[0] = B_.q[0]; dst[1] = B_.q[1];
    }
  } else if (t < 128 && tm != tn){
    // mirror: 32 rows x 2 octs (this half's 16 cols of the mirror tile)
    int idx = t - 64;
    int lr2 = idx >> 1, oct = idx & 1;
    int row = tn*32 + lr2, colb = tm*32 + half*16 + oct*8;
    if (row < 496){
      union { u16 h[8]; u64 q[2]; } B_;
      #pragma unroll
      for (int j = 0; j < 8; ++j) B_.h[j] = f2bf(red[0][oct*8 + j][lr2]);
      u64* dst = (u64*)&Bop2[stx(row, (rhoKBN << 5) + colb, 176)];
      dst[0] = B_.q[0]; dst[1] = B_.q[1];
    }
  }
}

extern "C" void kernel_launch(void* const* d_in, const int* in_sizes, int n_in,
                              void* d_out, int out_size, void* d_ws, size_t ws_size,
                              hipStream_t stream)
{
  (void)in_sizes; (void)n_in; (void)out_size;
  if (ws_size < WS_NEED) return;
  const float* rho0  = (const float*)d_in[0];
  // d_in[1] (H_real) provably does not affect the real forward output.
  const float* L     = (const float*)d_in[2];
  const float* rates = (const float*)d_in[3];
  float* dout = (float*)d_out;
  char* ws = (char*)d_ws;
  u16* Wall = (u16*)(ws + OFF_WALL);
  u16* Aop2 = (u16*)(ws + OFF_AOP2);
  u16* Bop2 = (u16*)(ws + OFF_BOP2);

  k0a<<<dim3((8*496*512 + 255)/256), dim3(256), 0, stream>>>(L, rates, Wall, Bop2);
  k0b<<<dim3(16,16,8), dim3(32,8), 0, stream>>>(L, rates, Aop2);
  k0c<<<dim3((496*512 + 255)/256), dim3(256), 0, stream>>>(rho0, Bop2, Wall, dout);
  // G = sum_k r_k L_k^T L_k -> Wall rows 3968.. (consumes SwC in Aop2)
  gemmG_k<<<dim3(8,8), dim3(256), 0, stream>>>(Aop2, Wall);

  for (int s = 0; s < 32; ++s){
    int rhoKB  = 144 + 16*(s & 1);
    int rhoKBN = 144 + 16*((s+1) & 1);
    // phase A: T_k = L~_k rho (k=0..7) and T9 = G rho
    phaseA_k<<<dim3(576), dim3(256), 0, stream>>>(Wall, Bop2, rhoKB, Aop2);
    // phase B: rho += DT*( sum_k T_k L~_k^T - 0.5(T9 + T9^T) ), output-split
    phaseB_k<<<dim3(272), dim3(512), 0, stream>>>(Aop2, Bop2, dout, rhoKBN);
  }
}

// Round 6
// 686.265 us; speedup vs baseline: 1.1076x; 1.1076x over previous
//
#include <hip/hip_runtime.h>

typedef unsigned short u16;
typedef unsigned long long u64;
typedef __attribute__((ext_vector_type(8))) __bf16 bf16x8;
typedef __attribute__((ext_vector_type(4))) float f32x4;

#define DT_STEP 0.01f

// ---- workspace layout (bytes) ----
// Staged layout: element (row,kk) of a [rows x K] K-major matrix at
//   off_u16 = ((row>>4)*KB + (kk>>5))*512 + (((kk>>3)&3)*16 + (row&15))*8 + (kk&7)
// -> a wave's MFMA fragment load is 16B/lane at base + lane*16B; 8
//    consecutive kk of one row are 16B contiguous (coalesced stores).
//    A (row-block, k-chunk) unit is 1KB, lane-linear -> global_load_lds-able;
//    consecutive k-chunks of one row-block are contiguous (2KB units OK).
//
// Wall : 4480 rows x 512 K (KB=16, 280 row-blocks)
// Aop2 : 496 rows x 5632 K (KB=176) : KB 0..127 Tflat, KB 128..143 T9
// Bop2 : 496 rows x 5632 K (KB=176) : KB 0..127 SwT, KB 144..175 rho slots
//
// R3 LESSON: device-scope fences in per-step kernels flush XCD L2 ->
//   phaseB refetches everything (70us). No cross-block protocols hot.
// R5 LESSON: output-splitting phaseB duplicates the B-strip (68->104MB
//   L2 traffic) and per-CU-BW x 256CU == aggregate L2 BW, so idle CUs
//   were NOT the constraint. PhaseB gap vs 3.8us traffic floor is
//   latency exposure (2 waves/SIMD) -> R6 widens to 16 waves/block.
static const size_t OFF_WALL = 0;
static const size_t OFF_AOP2 = 4587520;    // 280*16*512*2
static const size_t OFF_BOP2 = 10174464;   // + 31*176*512*2
static const size_t WS_NEED  = 16221440;   // proven available since R0

static __device__ __forceinline__ u16 f2bf(float x){
  unsigned u = __float_as_uint(x);
  u = u + 0x7FFFu + ((u >> 16) & 1u);   // RNE
  return (u16)(u >> 16);
}
static __device__ __forceinline__ float bf2f(u16 h){
  return __uint_as_float(((unsigned)h) << 16);
}

static __device__ __forceinline__ size_t stx(int row, int kk, int KB){
  return ((size_t)((row >> 4) * KB + (kk >> 5)) << 9)
       + (size_t)(((((kk >> 3) & 3) * 16) + (row & 15)) << 3) + (kk & 7);
}

// Rotated-register-pipeline NT GEMM K-loop on staged operands (all cached).
// Requires (NKT-DEPTH) % DEPTH == 0.  NKT==DEPTH -> fully prefetched.
template<int NKT, int DEPTH>
static __device__ __forceinline__ void kloop(
    f32x4 (&acc)[2][2], const u16* __restrict__ baseA,
    const u16* __restrict__ baseB, size_t strA, size_t strB)
{
  bf16x8 Ar[DEPTH][2], Br[DEPTH][2];
#define LDAB(p, kt) { const u16* pa = baseA + ((size_t)(kt) << 9);             \
    const u16* pb = baseB + ((size_t)(kt) << 9);                               \
    Ar[p][0] = *(const bf16x8*)pa; Ar[p][1] = *(const bf16x8*)(pa + strA);     \
    Br[p][0] = *(const bf16x8*)pb; Br[p][1] = *(const bf16x8*)(pb + strB); }
#define MF(p) \
    acc[0][0] = __builtin_amdgcn_mfma_f32_16x16x32_bf16(Ar[p][0], Br[p][0], acc[0][0], 0, 0, 0); \
    acc[0][1] = __builtin_amdgcn_mfma_f32_16x16x32_bf16(Ar[p][0], Br[p][1], acc[0][1], 0, 0, 0); \
    acc[1][0] = __builtin_amdgcn_mfma_f32_16x16x32_bf16(Ar[p][1], Br[p][0], acc[1][0], 0, 0, 0); \
    acc[1][1] = __builtin_amdgcn_mfma_f32_16x16x32_bf16(Ar[p][1], Br[p][1], acc[1][1], 0, 0, 0);
  #pragma unroll
  for (int p = 0; p < DEPTH; ++p){ LDAB(p, p) }
  for (int it = 0; it < NKT - DEPTH; it += DEPTH){
    #pragma unroll
    for (int p = 0; p < DEPTH; ++p){
      MF(p)
      LDAB(p, it + p + DEPTH)
    }
  }
  #pragma unroll
  for (int p = 0; p < DEPTH; ++p){ MF(p) }
#undef LDAB
#undef MF
}

// K0a: fill Wall k=0..7 (staged) and SwT region of Bop2. K-pads -> 0.
__global__ __launch_bounds__(256) void k0a(const float* __restrict__ L,
                                           const float* __restrict__ rates,
                                           u16* __restrict__ Wall,
                                           u16* __restrict__ Bop2){
  int id = blockIdx.x * 256 + threadIdx.x;
  if (id >= 8*496*512) return;
  int k   = id / (496*512);
  int rem = id - k*(496*512);
  int i   = rem >> 9;
  int j   = rem & 511;
  float rt = sqrtf(fabsf(rates[k]));
  float v = 0.0f;
  if (j < 496) v = rt * L[(size_t)k*246016 + i*496 + j];
  u16 h = f2bf(v);
  Wall[stx(k*496 + i, j, 16)] = h;
  Bop2[stx(i, (k << 9) + j, 176)] = h;
}

// K0b: SwC[i, k*512+j] = sqrt(r_k)*L_k[j,i] into Aop2 KB 0..127 (LDS
// transpose). Consumed once by gemmG, then overwritten by Tflat each step.
__global__ __launch_bounds__(256) void k0b(const float* __restrict__ L,
                                           const float* __restrict__ rates,
                                           u16* __restrict__ Aop2){
  __shared__ float tile[32][33];
  int k  = blockIdx.z;
  int i0 = blockIdx.x * 32;
  int j0 = blockIdx.y * 32;
  int tx = threadIdx.x, ty = threadIdx.y;  // 32 x 8
  float rt = sqrtf(fabsf(rates[k]));
  #pragma unroll
  for (int p = 0; p < 4; ++p){
    int j = j0 + ty + p*8;
    int i = i0 + tx;
    float v = 0.0f;
    if (j < 496 && i < 496) v = rt * L[(size_t)k*246016 + j*496 + i];
    tile[ty + p*8][tx] = v;
  }
  __syncthreads();
  #pragma unroll
  for (int p = 0; p < 4; ++p){
    int i = i0 + ty + p*8;
    int j = j0 + tx;
    if (i < 496) Aop2[stx(i, (k << 9) + j, 176)] = f2bf(tile[tx][ty + p*8]);
  }
}

// K0c: rho into Bop2 slot0, zero slot1, d_out = rho0, Wall pads zero.
__global__ __launch_bounds__(256) void k0c(const float* __restrict__ rho0,
                                           u16* __restrict__ Bop2,
                                           u16* __restrict__ Wall,
                                           float* __restrict__ dout){
  int id = blockIdx.x * 256 + threadIdx.x;
  if (id >= 496*512) return;
  int i = id >> 9, j = id & 511;
  float f = (j < 496) ? rho0[(size_t)i*496 + j] : 0.0f;
  Bop2[stx(i, 4608 + j, 176)] = f2bf(f);
  Bop2[stx(i, 5120 + j, 176)] = 0;
  if (j < 496) dout[(size_t)i*496 + j] = f;
  // Wall pad rows 4464..4479 (all cols)
  if (id < 8192) Wall[stx(4464 + (id >> 9), id & 511, 16)] = 0;
  // Wall G-block K-pad cols 496..511 for rows 3968..4463
  else if (id < 8192 + 7936){
    int idx = id - 8192;
    Wall[stx(3968 + (idx >> 4), 496 + (idx & 15), 16)] = 0;
  }
}

// G = SwC * SwC^T (once) -> Wall rows 3968..4463 (staged, KB=16).
__global__ __launch_bounds__(256, 2) void gemmG_k(
    const u16* __restrict__ Asrc, u16* __restrict__ Wall){
  const int t = threadIdx.x, lane = t & 63, w = t >> 6;
  const int wm = w & 1, wn = w >> 1;
  const int tm = blockIdx.x, tn = blockIdx.y;
  const size_t laneu = (size_t)lane * 8;
  const size_t str = (size_t)176 << 9;
  const u16* baseA = Asrc + (((size_t)(tm*4 + wm*2) * 176) << 9) + laneu;
  const u16* baseB = Asrc + (((size_t)(tn*4 + wn*2) * 176) << 9) + laneu;
  f32x4 acc[2][2];
  #pragma unroll
  for (int a = 0; a < 2; ++a)
    #pragma unroll
    for (int b = 0; b < 2; ++b)
      acc[a][b] = (f32x4){0.f, 0.f, 0.f, 0.f};
  kloop<128, 4>(acc, baseA, baseB, str, str);
  const int quad = lane >> 4, c16 = lane & 15;
  #pragma unroll
  for (int mi = 0; mi < 2; ++mi)
  #pragma unroll
  for (int ni = 0; ni < 2; ++ni)
  #pragma unroll
  for (int r = 0; r < 4; ++r){
    int row = tm*64 + wm*32 + mi*16 + quad*4 + r;
    int col = tn*64 + wn*32 + ni*16 + c16;
    if (row < 496 && col < 496)
      Wall[stx(3968 + row, col, 16)] = f2bf(acc[mi][ni][r]);
  }
}

// Phase A v3 (R3/R4-measured ~9.5us/step incl. launch gap): LDS-staged via
// global_load_lds width=16, 2-chunk (2KB) units: 8 iterations x 8 MFMA,
// 16 barriers, vmcnt(4), 32KB LDS dbuf.
typedef const __attribute__((address_space(1))) unsigned char* gas1p;
typedef __attribute__((address_space(3))) unsigned char* las3p;

__global__ __launch_bounds__(256, 4) void phaseA_k(
    const u16* __restrict__ Wall, const u16* __restrict__ Bop2,
    int rhoKB, u16* __restrict__ Aop2)
{
  __shared__ char smraw[32768];                     // 2 bufs x 8 units x 2KB
  u16 (*stage)[8][1024] = (u16 (*)[8][1024])smraw;  // [2][8 units][1024 u16]
  float (*T)[66] = (float (*)[66])smraw;            // epilogue transpose alias

  int b = blockIdx.x;
  int x = b & 7, i = b >> 3;
  int tm = x*9 + (i % 9);
  int tn = i / 9;
  if (tm >= 70) return;                      // block-uniform early exit
  const int t = threadIdx.x, lane = t & 63, w = t >> 6;
  const int wm = w & 1, wn = w >> 1;
  const int lane8 = lane * 8;                // lane*16B in u16 units

  // Wave w stages A row-block tm*4+w (Wall) and B row-block tn*4+w (rho).
  const u16* gAw = Wall + (((size_t)(tm*4 + w) * 16) << 9) + lane8;
  const u16* gBw = Bop2 + (((size_t)(tn*4 + w) * 176 + rhoKB) << 9) + lane8;

  // stage 2 consecutive k-chunks (2j, 2j+1) per unit: 4 loads/wave/iter
#define STAGE_A(bi, j) {                                                       \
    size_t ko = (size_t)((j) * 2) << 9;                                        \
    __builtin_amdgcn_global_load_lds((gas1p)(gAw + ko),                        \
        (las3p)&stage[bi][w][0], 16, 0, 0);                                    \
    __builtin_amdgcn_global_load_lds((gas1p)(gAw + ko + 512),                  \
        (las3p)&stage[bi][w][512], 16, 0, 0);                                  \
    __builtin_amdgcn_global_load_lds((gas1p)(gBw + ko),                        \
        (las3p)&stage[bi][4 + w][0], 16, 0, 0);                                \
    __builtin_amdgcn_global_load_lds((gas1p)(gBw + ko + 512),                  \
        (las3p)&stage[bi][4 + w][512], 16, 0, 0); }

  f32x4 acc[2][2];
  #pragma unroll
  for (int a = 0; a < 2; ++a)
    #pragma unroll
    for (int c = 0; c < 2; ++c)
      acc[a][c] = (f32x4){0.f, 0.f, 0.f, 0.f};

#define COMPUTE_A(bi) {                                                        \
    _Pragma("unroll")                                                          \
    for (int c = 0; c < 2; ++c){                                               \
      bf16x8 a0 = *(const bf16x8*)&stage[bi][wm*2 + 0][c*512 + lane8];         \
      bf16x8 a1 = *(const bf16x8*)&stage[bi][wm*2 + 1][c*512 + lane8];         \
      bf16x8 b0 = *(const bf16x8*)&stage[bi][4 + wn*2 + 0][c*512 + lane8];     \
      bf16x8 b1 = *(const bf16x8*)&stage[bi][4 + wn*2 + 1][c*512 + lane8];     \
      acc[0][0] = __builtin_amdgcn_mfma_f32_16x16x32_bf16(a0, b0, acc[0][0], 0, 0, 0); \
      acc[0][1] = __builtin_amdgcn_mfma_f32_16x16x32_bf16(a0, b1, acc[0][1], 0, 0, 0); \
      acc[1][0] = __builtin_amdgcn_mfma_f32_16x16x32_bf16(a1, b0, acc[1][0], 0, 0, 0); \
      acc[1][1] = __builtin_amdgcn_mfma_f32_16x16x32_bf16(a1, b1, acc[1][1], 0, 0, 0); \
    } }

  // prologue: 2 double-chunk units in flight (8 loads)
  STAGE_A(0, 0)
  STAGE_A(1, 1)
  int cur = 0;
  #pragma unroll
  for (int j = 0; j < 7; ++j){
    asm volatile("s_waitcnt vmcnt(4)" ::: "memory");  // oldest unit landed
    __builtin_amdgcn_s_barrier();                     // visible to all waves
    COMPUTE_A(cur)
    asm volatile("" ::: "memory");
    __builtin_amdgcn_s_barrier();                     // all reads of cur done
    if (j < 6) STAGE_A(cur, j + 2)                    // restage same parity
    cur ^= 1;
  }
  // peeled last unit (j = 7): drain fully
  asm volatile("s_waitcnt vmcnt(0)" ::: "memory");
  __builtin_amdgcn_s_barrier();
  COMPUTE_A(cur)
#undef STAGE_A
#undef COMPUTE_A

  __syncthreads();   // all waves done with stage[] before aliasing as T

  const int quad = lane >> 4, c16 = lane & 15;
  #pragma unroll
  for (int mi = 0; mi < 2; ++mi)
  #pragma unroll
  for (int ni = 0; ni < 2; ++ni)
  #pragma unroll
  for (int r = 0; r < 4; ++r)
    T[wm*32 + mi*16 + quad*4 + r][wn*32 + ni*16 + c16] = acc[mi][ni][r];
  __syncthreads();
  #pragma unroll
  for (int rep = 0; rep < 2; ++rep){
    int tt = t + rep*256;
    int lr = tt >> 3, oct = tt & 7;
    int row = tm*64 + lr;
    if (row < 4464){
      int colb = tn*64 + oct*8;
      int k = row / 496, i2 = row - k*496;
      union { u16 h[8]; u64 q[2]; } P;
      #pragma unroll
      for (int j = 0; j < 8; ++j)
        P.h[j] = (colb + j < 496) ? f2bf(T[lr][oct*8 + j]) : (u16)0;
      u64* dst = (u64*)&Aop2[stx(i2, (k << 9) + colb, 176)];
      dst[0] = P.q[0]; dst[1] = P.q[1];
    }
  }
}

// Phase-B pair decode with XCD quadrant grouping (R5-proven).
static __device__ __forceinline__ void pairDecode(int b, int& tm, int& tn){
  const int x = b & 7;
  const int o = b >> 3;
  if (x < 6 && o < 16){
    const int qa[6] = {0,0,0,1,1,2};
    const int qb[6] = {1,2,3,2,3,3};
    tm = qa[x]*4 + (o >> 2);
    tn = qb[x]*4 + (o & 3);
  } else {
    int n, grp;
    if (x == 6){ grp = 0; n = o; }
    else if (x == 7){ grp = 1; n = o; }
    else if (x < 3){ grp = 0; n = 17 + x; }
    else { grp = 1; n = 17 + (x - 3); }
    int qbase = (grp == 0) ? ((n < 10) ? 0 : 1) : ((n < 10) ? 2 : 3);
    int m = (n < 10) ? n : n - 10;
    int ii = 0;
    while (m >= 4 - ii){ m -= 4 - ii; ++ii; }
    tm = qbase*4 + ii;
    tn = qbase*4 + ii + m;
  }
}

// Phase B v4 (wide): 136 blocks (no strip duplication — R5 lesson), but
// 1024 threads = 16 waves (4 waves/SIMD) for 2x latency hiding. Each wave
// covers 8 k-chunks with kloop<8,8> (fully prefetched: 32 loads then 32
// MFMA). T9 pair + old dout prefetched before the reduce barrier. 16-way
// LDS reduce, then same block-local epilogue as R4.
__global__ __launch_bounds__(1024, 1) void phaseB_k(
    const u16* __restrict__ Aop2, u16* __restrict__ Bop2,
    float* __restrict__ dout, int rhoKBN)
{
  __shared__ float red[16][32][33];          // 67.6 KB
  const int t = threadIdx.x, lane = t & 63, w = t >> 6;   // w in 0..15
  int tm, tn;
  pairDecode(blockIdx.x, tm, tn);            // tm <= tn
  const size_t laneu = (size_t)lane * 8;
  const size_t str = (size_t)176 << 9;
  const u16* baseA = Aop2 + (((size_t)(tm*2) * 176) << 9) + laneu
                   + ((size_t)(w*8) << 9);
  const u16* baseB = Bop2 + (((size_t)(tn*2) * 176) << 9) + laneu
                   + ((size_t)(w*8) << 9);

  f32x4 acc[2][2];
  #pragma unroll
  for (int a = 0; a < 2; ++a)
    #pragma unroll
    for (int c = 0; c < 2; ++c)
      acc[a][c] = (f32x4){0.f, 0.f, 0.f, 0.f};
  kloop<8, 8>(acc, baseA, baseB, str, str);

  const int quad = lane >> 4, c16 = lane & 15;
  #pragma unroll
  for (int mi = 0; mi < 2; ++mi)
  #pragma unroll
  for (int ni = 0; ni < 2; ++ni)
  #pragma unroll
  for (int r = 0; r < 4; ++r)
    red[w][mi*16 + quad*4 + r][ni*16 + c16] = acc[mi][ni][r];

  // prefetch T9 pair + old rho under the barrier+reduce (benign OOB reads
  // of Aop2 row-block 31 stay inside WS — see header comment)
  const int lr = t >> 5, lc = t & 31;        // 32x32 elems, 1/thread
  const int row = tm*32 + lr, col = tn*32 + lc;
  const float t9a = bf2f(Aop2[stx(row, 4096 + col, 176)]);
  const float t9b = bf2f(Aop2[stx(col, 4096 + row, 176)]);
  const bool act = (row < 496) && (col < 496);
  float dold = 0.0f;
  if (act) dold = dout[row*496 + col];
  __syncthreads();

  // pass 1: 16-way reduce + T9 anticommutator + rho update; rnew -> red[0]
  {
    float sum = 0.0f;
    #pragma unroll
    for (int ww = 0; ww < 16; ++ww) sum += red[ww][lr][lc];
    float rnew = 0.0f;
    if (act){
      rnew = dold + DT_STEP * (sum - 0.5f*(t9a + t9b));
      dout[row*496 + col] = rnew;
      if (tm != tn) dout[col*496 + row] = rnew;
    }
    red[0][lr][lc] = rnew;
  }
  __syncthreads();

  // pass 2: staged bf16 rho, 16B coalesced stores (threads 0..255)
  if (t < 256){
    int tt = t & 127;
    int plr = tt >> 2, oct = tt & 3;
    if (t < 128){
      int prow = tm*32 + plr, colb = tn*32 + oct*8;
      if (prow < 496 && colb < 496){
        union { u16 h[8]; u64 q[2]; } B_;
        #pragma unroll
        for (int j = 0; j < 8; ++j) B_.h[j] = f2bf(red[0][plr][oct*8 + j]);
        u64* dst = (u64*)&Bop2[stx(prow, (rhoKBN << 5) + colb, 176)];
        dst[0] = B_.q[0]; dst[1] = B_.q[1];
      }
    } else if (tm != tn){
      int prow = tn*32 + plr, colb = tm*32 + oct*8;   // mirror tile
      if (prow < 496){
        union { u16 h[8]; u64 q[2]; } B_;
        #pragma unroll
        for (int j = 0; j < 8; ++j) B_.h[j] = f2bf(red[0][oct*8 + j][plr]);
        u64* dst = (u64*)&Bop2[stx(prow, (rhoKBN << 5) + colb, 176)];
        dst[0] = B_.q[0]; dst[1] = B_.q[1];
      }
    }
  }
}

extern "C" void kernel_launch(void* const* d_in, const int* in_sizes, int n_in,
                              void* d_out, int out_size, void* d_ws, size_t ws_size,
                              hipStream_t stream)
{
  (void)in_sizes; (void)n_in; (void)out_size;
  if (ws_size < WS_NEED) return;
  const float* rho0  = (const float*)d_in[0];
  // d_in[1] (H_real) provably does not affect the real forward output.
  const float* L     = (const float*)d_in[2];
  const float* rates = (const float*)d_in[3];
  float* dout = (float*)d_out;
  char* ws = (char*)d_ws;
  u16* Wall = (u16*)(ws + OFF_WALL);
  u16* Aop2 = (u16*)(ws + OFF_AOP2);
  u16* Bop2 = (u16*)(ws + OFF_BOP2);

  k0a<<<dim3((8*496*512 + 255)/256), dim3(256), 0, stream>>>(L, rates, Wall, Bop2);
  k0b<<<dim3(16,16,8), dim3(32,8), 0, stream>>>(L, rates, Aop2);
  k0c<<<dim3((496*512 + 255)/256), dim3(256), 0, stream>>>(rho0, Bop2, Wall, dout);
  // G = sum_k r_k L_k^T L_k -> Wall rows 3968.. (consumes SwC in Aop2)
  gemmG_k<<<dim3(8,8), dim3(256), 0, stream>>>(Aop2, Wall);

  for (int s = 0; s < 32; ++s){
    int rhoKB  = 144 + 16*(s & 1);
    int rhoKBN = 144 + 16*((s+1) & 1);
    // phase A: T_k = L~_k rho (k=0..7) and T9 = G rho
    phaseA_k<<<dim3(576), dim3(256), 0, stream>>>(Wall, Bop2, rhoKB, Aop2);
    // phase B: rho += DT*( sum_k T_k L~_k^T - 0.5(T9 + T9^T) ), 16-wave
    phaseB_k<<<dim3(136), dim3(1024), 0, stream>>>(Aop2, Bop2, dout, rhoKBN);
  }
}